// Round 2
// baseline (661.372 us; speedup 1.0000x reference)
//
#include <hip/hip_runtime.h>

#define BB 32
#define TT 4096
#define DD 512
#define HH 8
#define HDD 64
#define SCALE_F 0.125f   // 64^-0.5 exact
#define CHUNKS 32
#define TC (TT / CHUNKS) // 128

// ---------------- A: q = enc[:, -1, :] @ Wq.T ; u[b,h,:] = SCALE * Wk_h^T q_h ----
__global__ __launch_bounds__(256) void k_qu(const float* __restrict__ enc,
                                            const float* __restrict__ Wq,
                                            const float* __restrict__ Wk,
                                            float* __restrict__ u) {
    __shared__ float x[DD];
    __shared__ float qs[DD];
    int b = blockIdx.x, tid = threadIdx.x;
    const float* el = enc + ((size_t)b * TT + (TT - 1)) * DD;
    for (int i = tid; i < DD; i += 256) x[i] = el[i];
    __syncthreads();
    for (int i = tid; i < DD; i += 256) {
        const float4* wr = (const float4*)(Wq + (size_t)i * DD);
        float acc = 0.f;
#pragma unroll 4
        for (int d = 0; d < DD / 4; ++d) {
            float4 w = wr[d];
            acc += w.x * x[4 * d] + w.y * x[4 * d + 1] + w.z * x[4 * d + 2] + w.w * x[4 * d + 3];
        }
        qs[i] = acc;
    }
    __syncthreads();
    for (int k = 0; k < 16; ++k) {
        int o = tid + 256 * k;          // h is uniform within each k-iteration
        int h = o >> 9, d = o & 511;
        float acc = 0.f;
#pragma unroll 8
        for (int j = 0; j < HDD; ++j)
            acc += qs[h * HDD + j] * Wk[(size_t)(h * HDD + j) * DD + d];
        u[(size_t)b * HH * DD + o] = acc * SCALE_F;
    }
}

// ---------------- B: scores[b,t,h] = u[b,h,:] . enc[b,t,:]  ([B,T,H] layout) ----
// 1 wave per row; reduce via wave-local LDS transpose (15 ds-ops/row vs 48 swizzles).
__global__ __launch_bounds__(256) void k_scores(const float* __restrict__ enc,
                                                const float* __restrict__ u,
                                                float* __restrict__ scores) {
    __shared__ float red[4][64 * 10];   // per-wave, stride 10 floats to break banks
    int blk = blockIdx.x;
    int b = blk >> 6;
    int t0 = (blk & 63) * 64;
    int wave = threadIdx.x >> 6, lane = threadIdx.x & 63;
    float* W = red[wave];
    float4 uA[HH], uB[HH];
    const float* ub = u + (size_t)b * HH * DD;
#pragma unroll
    for (int h = 0; h < HH; ++h) {
        uA[h] = *(const float4*)(ub + h * DD + 4 * lane);
        uB[h] = *(const float4*)(ub + h * DD + 256 + 4 * lane);
    }
    int hh = lane >> 3, j0 = lane & 7;
    for (int tt = wave; tt < 64; tt += 4) {
        int t = t0 + tt;
        const float* row = enc + ((size_t)b * TT + t) * DD;
        float4 e0 = *(const float4*)(row + 4 * lane);
        float4 e1 = *(const float4*)(row + 256 + 4 * lane);
        float acc[HH];
#pragma unroll
        for (int h = 0; h < HH; ++h)
            acc[h] = uA[h].x * e0.x + uA[h].y * e0.y + uA[h].z * e0.z + uA[h].w * e0.w
                   + uB[h].x * e1.x + uB[h].y * e1.y + uB[h].z * e1.z + uB[h].w * e1.w;
        // lane -> LDS row (stride 10 floats), 4x ds_write_b64
        float* wrp = W + lane * 10;
        *(float2*)(wrp + 0) = make_float2(acc[0], acc[1]);
        *(float2*)(wrp + 2) = make_float2(acc[2], acc[3]);
        *(float2*)(wrp + 4) = make_float2(acc[4], acc[5]);
        *(float2*)(wrp + 6) = make_float2(acc[6], acc[7]);
        // gather: lane (hh, j0) sums sources j0*8..j0*8+7 for head hh
        float s = 0.f;
#pragma unroll
        for (int k = 0; k < 8; ++k) s += W[(j0 * 8 + k) * 10 + hh];
        s += __shfl_xor(s, 1, 64);
        s += __shfl_xor(s, 2, 64);
        s += __shfl_xor(s, 4, 64);
        if (j0 == 0) scores[((size_t)b * TT + t) * HH + hh] = s;
    }
}

// ---------------- C: softmax over t per (b,h); [B,T,H] layout ----------------
__global__ __launch_bounds__(256) void k_softmax(const float* __restrict__ scores,
                                                 float* __restrict__ weights) {
    int b = blockIdx.x / HH, h = blockIdx.x % HH;
    const float* sp = scores + (size_t)b * TT * HH + h;
    float* wp = weights + (size_t)b * TT * HH + h;
    int tid = threadIdx.x;
    int wave = tid >> 6, lane = tid & 63;
    __shared__ float red[8];
    float vals[TT / 256];
#pragma unroll
    for (int k = 0; k < TT / 256; ++k) vals[k] = sp[(size_t)(tid + 256 * k) * HH];
    float m = -1e30f;
#pragma unroll
    for (int k = 0; k < TT / 256; ++k) m = fmaxf(m, vals[k]);
#pragma unroll
    for (int msk = 1; msk < 64; msk <<= 1) m = fmaxf(m, __shfl_xor(m, msk, 64));
    if (lane == 0) red[wave] = m;
    __syncthreads();
    m = fmaxf(fmaxf(red[0], red[1]), fmaxf(red[2], red[3]));
    float s = 0.f;
#pragma unroll
    for (int k = 0; k < TT / 256; ++k) { vals[k] = __expf(vals[k] - m); s += vals[k]; }
#pragma unroll
    for (int msk = 1; msk < 64; msk <<= 1) s += __shfl_xor(s, msk, 64);
    __syncthreads();
    if (lane == 0) red[4 + wave] = s;
    __syncthreads();
    s = red[4] + red[5] + red[6] + red[7];
    float inv = 1.0f / s;
#pragma unroll
    for (int k = 0; k < TT / 256; ++k) wp[(size_t)(tid + 256 * k) * HH] = vals[k] * inv;
}

// ---------------- E: weighted enc-sum partials + fused head-mean --------------
// block = (b, chunk of 128 rows); halves of the block take even/odd rows.
// partial[b, cc, h, d], cc = c*2 + half  (64 effective chunks)
__global__ __launch_bounds__(256) void k_wsum(const float* __restrict__ enc,
                                              const float* __restrict__ weights,
                                              float* __restrict__ partial,
                                              float* __restrict__ out1) {
    __shared__ float wl[TC * HH]; // 128 rows x 8 heads
    int b = blockIdx.x / CHUNKS, c = blockIdx.x % CHUNKS;
    int t0 = c * TC, tid = threadIdx.x;
    *(float4*)(wl + tid * 4) =
        *(const float4*)(weights + ((size_t)b * TT + t0) * HH + tid * 4);
    __syncthreads();
    if (tid < TC) { // fused wmean: out1[b,t] = mean_h w[b,t,h]
        const float4* wp = (const float4*)(wl + tid * HH);
        float4 a = wp[0], d4 = wp[1];
        out1[(size_t)b * TT + t0 + tid] =
            (a.x + a.y + a.z + a.w + d4.x + d4.y + d4.z + d4.w) * 0.125f;
    }
    int half = tid >> 7, dtid = tid & 127;
    float4 acc[HH];
#pragma unroll
    for (int h = 0; h < HH; ++h) acc[h] = make_float4(0.f, 0.f, 0.f, 0.f);
#pragma unroll 2
    for (int i = 0; i < TC / 2; ++i) {
        int r = half + 2 * i;
        float4 e = *(const float4*)(enc + ((size_t)b * TT + t0 + r) * DD + dtid * 4);
        const float* wr = wl + r * HH;
        float4 w0 = *(const float4*)wr;       // broadcast
        float4 w1 = *(const float4*)(wr + 4); // broadcast
        acc[0].x += w0.x * e.x; acc[0].y += w0.x * e.y; acc[0].z += w0.x * e.z; acc[0].w += w0.x * e.w;
        acc[1].x += w0.y * e.x; acc[1].y += w0.y * e.y; acc[1].z += w0.y * e.z; acc[1].w += w0.y * e.w;
        acc[2].x += w0.z * e.x; acc[2].y += w0.z * e.y; acc[2].z += w0.z * e.z; acc[2].w += w0.z * e.w;
        acc[3].x += w0.w * e.x; acc[3].y += w0.w * e.y; acc[3].z += w0.w * e.z; acc[3].w += w0.w * e.w;
        acc[4].x += w1.x * e.x; acc[4].y += w1.x * e.y; acc[4].z += w1.x * e.z; acc[4].w += w1.x * e.w;
        acc[5].x += w1.y * e.x; acc[5].y += w1.y * e.y; acc[5].z += w1.y * e.z; acc[5].w += w1.y * e.w;
        acc[6].x += w1.z * e.x; acc[6].y += w1.z * e.y; acc[6].z += w1.z * e.z; acc[6].w += w1.z * e.w;
        acc[7].x += w1.w * e.x; acc[7].y += w1.w * e.y; acc[7].z += w1.w * e.z; acc[7].w += w1.w * e.w;
    }
    int cc = c * 2 + half;
    float* pp = partial + (size_t)(b * 64 + cc) * HH * DD + dtid * 4;
#pragma unroll
    for (int h = 0; h < HH; ++h) *(float4*)(pp + h * DD) = acc[h];
}

// ---------------- F: ctx = sum partials; ctxv = blockdiag(Wv) ctx; out0 = Wo ctxv
__global__ __launch_bounds__(256) void k_tail(const float* __restrict__ partial,
                                              const float* __restrict__ Wv,
                                              const float* __restrict__ Wo,
                                              float* __restrict__ out0) {
    __shared__ float cx[HH * DD]; // ctx[b] : r = h*512 + d
    __shared__ float cv[DD];
    int b = blockIdx.x, tid = threadIdx.x;
    for (int k = 0; k < 16; ++k) {
        int r = tid + 256 * k;
        const float* pp = partial + (size_t)b * 64 * HH * DD + r;
        float acc = 0.f;
#pragma unroll 8
        for (int ccv = 0; ccv < 64; ++ccv) acc += pp[(size_t)ccv * HH * DD];
        cx[r] = acc;
    }
    __syncthreads();
    for (int k = 0; k < 2; ++k) {
        int i = tid + 256 * k;
        int h = i >> 6;
        const float4* wr = (const float4*)(Wv + (size_t)i * DD);
        const float* ccp = cx + h * DD;
        float acc = 0.f;
#pragma unroll 4
        for (int d = 0; d < DD / 4; ++d) {
            float4 w = wr[d];
            acc += w.x * ccp[4 * d] + w.y * ccp[4 * d + 1] + w.z * ccp[4 * d + 2] + w.w * ccp[4 * d + 3];
        }
        cv[i] = acc;
    }
    __syncthreads();
    for (int k = 0; k < 2; ++k) {
        int o = tid + 256 * k;
        const float4* wr = (const float4*)(Wo + (size_t)o * DD);
        float acc = 0.f;
#pragma unroll 4
        for (int d = 0; d < DD / 4; ++d) {
            float4 w = wr[d];
            acc += w.x * cv[4 * d] + w.y * cv[4 * d + 1] + w.z * cv[4 * d + 2] + w.w * cv[4 * d + 3];
        }
        out0[(size_t)b * DD + o] = acc;
    }
}

extern "C" void kernel_launch(void* const* d_in, const int* in_sizes, int n_in,
                              void* d_out, int out_size, void* d_ws, size_t ws_size,
                              hipStream_t stream) {
    const float* enc = (const float*)d_in[0];
    const float* Wq  = (const float*)d_in[1];
    const float* Wk  = (const float*)d_in[2];
    const float* Wv  = (const float*)d_in[3];
    const float* Wo  = (const float*)d_in[4];

    float* ws = (float*)d_ws;
    float* u       = ws;                               // B*H*D   = 131072
    float* scores  = u + (size_t)BB * HH * DD;         // B*T*H   = 1048576
    float* weights = scores + (size_t)BB * TT * HH;    // B*T*H   = 1048576
    float* partial = weights + (size_t)BB * TT * HH;   // B*64*H*D = 8388608
    // total ~10.6M floats (~42 MB)

    float* out0 = (float*)d_out;          // [B, D]
    float* out1 = out0 + BB * DD;         // [B, T]

    hipLaunchKernelGGL(k_qu,      dim3(BB),           dim3(256), 0, stream, enc, Wq, Wk, u);
    hipLaunchKernelGGL(k_scores,  dim3(BB * 64),      dim3(256), 0, stream, enc, u, scores);
    hipLaunchKernelGGL(k_softmax, dim3(BB * HH),      dim3(256), 0, stream, scores, weights);
    hipLaunchKernelGGL(k_wsum,    dim3(BB * CHUNKS),  dim3(256), 0, stream, enc, weights, partial, out1);
    hipLaunchKernelGGL(k_tail,    dim3(BB),           dim3(256), 0, stream, partial, Wv, Wo, out0);
}

// Round 3
// 521.241 us; speedup vs baseline: 1.2688x; 1.2688x over previous
//
#include <hip/hip_runtime.h>

#define BB 32
#define TT 4096
#define DD 512
#define HH 8
#define HDD 64
#define SCALE_F 0.125f   // 64^-0.5 exact
#define CHUNKS 32
#define TC 128           // rows per wsum chunk

// ---------------- A: u[b,h,:] = SCALE * Wk_h^T (Wq_h . enc[b,-1,:]) ----------
// grid = B*H blocks.
__global__ __launch_bounds__(256) void k_qu(const float* __restrict__ enc,
                                            const float* __restrict__ Wq,
                                            const float* __restrict__ Wk,
                                            float* __restrict__ u) {
    __shared__ float x[DD];
    __shared__ float qh[HDD];
    int b = blockIdx.x >> 3, h = blockIdx.x & 7;
    int tid = threadIdx.x;
    const float* el = enc + ((size_t)b * TT + (TT - 1)) * DD;
    for (int i = tid; i < DD; i += 256) x[i] = el[i];
    __syncthreads();
    if (tid < HDD) {
        const float4* wr = (const float4*)(Wq + (size_t)(h * HDD + tid) * DD);
        float acc = 0.f;
#pragma unroll 4
        for (int d = 0; d < DD / 4; ++d) {
            float4 w = wr[d];
            acc += w.x * x[4 * d] + w.y * x[4 * d + 1] + w.z * x[4 * d + 2] + w.w * x[4 * d + 3];
        }
        qh[tid] = acc;
    }
    __syncthreads();
#pragma unroll
    for (int k = 0; k < 2; ++k) {
        int d = tid + 256 * k;
        float acc = 0.f;
#pragma unroll 8
        for (int j = 0; j < HDD; ++j)
            acc += qh[j] * Wk[(size_t)(h * HDD + j) * DD + d];
        u[(size_t)(b * HH + h) * DD + d] = acc * SCALE_F;
    }
}

// ---------------- B: scores[b,h,t] = u[b,h,:] . enc[b,t,:]  ([B,H,T] layout) --
// 1 wave per t-row; folding butterfly: 10 shfls/row instead of 48.
__global__ __launch_bounds__(256) void k_scores(const float* __restrict__ enc,
                                                const float* __restrict__ u,
                                                float* __restrict__ scores) {
    __shared__ float stile[HH][66];   // 64 t-cols, +2 pad
    int b = blockIdx.x >> 6;
    int t0 = (blockIdx.x & 63) * 64;
    int wave = threadIdx.x >> 6, lane = threadIdx.x & 63;
    const float* ub = u + (size_t)b * HH * DD;
    float4 uA[HH], uB[HH];
#pragma unroll
    for (int h = 0; h < HH; ++h) {
        uA[h] = *(const float4*)(ub + h * DD + 4 * lane);
        uB[h] = *(const float4*)(ub + h * DD + 256 + 4 * lane);
    }
    bool b3 = (lane & 8) != 0, b4 = (lane & 16) != 0, b5 = (lane & 32) != 0;
    int myh = ((lane >> 3) & 1) * 4 + ((lane >> 4) & 1) * 2 + ((lane >> 5) & 1);
    for (int tt = wave; tt < 64; tt += 4) {
        int t = t0 + tt;
        const float* row = enc + ((size_t)b * TT + t) * DD;
        float4 e0 = *(const float4*)(row + 4 * lane);
        float4 e1 = *(const float4*)(row + 256 + 4 * lane);
        float a[HH];
#pragma unroll
        for (int h = 0; h < HH; ++h)
            a[h] = uA[h].x * e0.x + uA[h].y * e0.y + uA[h].z * e0.z + uA[h].w * e0.w
                 + uB[h].x * e1.x + uB[h].y * e1.y + uB[h].z * e1.z + uB[h].w * e1.w;
        // fold mask 8: 8 -> 4 (kept head = b3*4 + j)
        float s[4];
#pragma unroll
        for (int j = 0; j < 4; ++j) {
            float snd = b3 ? a[j] : a[j + 4];
            float kp  = b3 ? a[j + 4] : a[j];
            s[j] = kp + __shfl_xor(snd, 8, 64);
        }
        // fold mask 16: 4 -> 2 (kept head = b3*4 + b4*2 + j)
        float p[2];
#pragma unroll
        for (int j = 0; j < 2; ++j) {
            float snd = b4 ? s[j] : s[j + 2];
            float kp  = b4 ? s[j + 2] : s[j];
            p[j] = kp + __shfl_xor(snd, 16, 64);
        }
        // fold mask 32: 2 -> 1 (head = b3*4 + b4*2 + b5)
        float snd = b5 ? p[0] : p[1];
        float q0 = (b5 ? p[1] : p[0]) + __shfl_xor(snd, 32, 64);
        q0 += __shfl_xor(q0, 1, 64);
        q0 += __shfl_xor(q0, 2, 64);
        q0 += __shfl_xor(q0, 4, 64);
        if ((lane & 7) == 0) stile[myh][tt] = q0;
    }
    __syncthreads();
#pragma unroll
    for (int k = 0; k < 2; ++k) {
        int idx = threadIdx.x + 256 * k;
        int h = idx >> 6, tt = idx & 63;
        scores[(size_t)(b * HH + h) * TT + t0 + tt] = stile[h][tt];
    }
}

// ---------------- C: softmax over t per (b,h); [B,H,T] rows contiguous --------
__global__ __launch_bounds__(256) void k_softmax(const float* __restrict__ scores,
                                                 float* __restrict__ weights) {
    const float* sp = scores + (size_t)blockIdx.x * TT;
    float* wp = weights + (size_t)blockIdx.x * TT;
    int tid = threadIdx.x;
    int wave = tid >> 6, lane = tid & 63;
    __shared__ float red[8];
    float4 v[4];
#pragma unroll
    for (int k = 0; k < 4; ++k) v[k] = *(const float4*)(sp + 4 * (tid + 256 * k));
    float m = -1e30f;
#pragma unroll
    for (int k = 0; k < 4; ++k)
        m = fmaxf(m, fmaxf(fmaxf(v[k].x, v[k].y), fmaxf(v[k].z, v[k].w)));
#pragma unroll
    for (int msk = 1; msk < 64; msk <<= 1) m = fmaxf(m, __shfl_xor(m, msk, 64));
    if (lane == 0) red[wave] = m;
    __syncthreads();
    m = fmaxf(fmaxf(red[0], red[1]), fmaxf(red[2], red[3]));
    float s = 0.f;
#pragma unroll
    for (int k = 0; k < 4; ++k) {
        v[k].x = __expf(v[k].x - m); v[k].y = __expf(v[k].y - m);
        v[k].z = __expf(v[k].z - m); v[k].w = __expf(v[k].w - m);
        s += v[k].x + v[k].y + v[k].z + v[k].w;
    }
#pragma unroll
    for (int msk = 1; msk < 64; msk <<= 1) s += __shfl_xor(s, msk, 64);
    __syncthreads();
    if (lane == 0) red[4 + wave] = s;
    __syncthreads();
    s = red[4] + red[5] + red[6] + red[7];
    float inv = 1.0f / s;
#pragma unroll
    for (int k = 0; k < 4; ++k) {
        v[k].x *= inv; v[k].y *= inv; v[k].z *= inv; v[k].w *= inv;
        *(float4*)(wp + 4 * (tid + 256 * k)) = v[k];
    }
}

// ---------------- E: partial[b,c,h,d] = sum_{t in chunk} w[b,h,t]*enc[b,t,d] --
// + fused head-mean. Block = 2 row-groups of 128 lanes; LDS half-merge.
__global__ __launch_bounds__(256) void k_wsum(const float* __restrict__ enc,
                                              const float* __restrict__ weights,
                                              float* __restrict__ partial,
                                              float* __restrict__ out1) {
    __shared__ float wl[HH * TC];   // 4 KiB, [h][t]
    __shared__ float mrg[HH * DD];  // 16 KiB
    int b = blockIdx.x / CHUNKS, c = blockIdx.x % CHUNKS;
    int t0 = c * TC, tid = threadIdx.x;
    {
        int h = tid >> 5, i0 = (tid & 31) * 4;
        *(float4*)(wl + h * TC + i0) =
            *(const float4*)(weights + (size_t)(b * HH + h) * TT + t0 + i0);
    }
    __syncthreads();
    if (tid < TC) { // fused wmean
        float s = 0.f;
#pragma unroll
        for (int h = 0; h < HH; ++h) s += wl[h * TC + tid];
        out1[(size_t)b * TT + t0 + tid] = s * 0.125f;
    }
    int grp = tid >> 7, gl = tid & 127;
    float4 acc[HH];
#pragma unroll
    for (int h = 0; h < HH; ++h) acc[h] = make_float4(0.f, 0.f, 0.f, 0.f);
#pragma unroll 4
    for (int i = 0; i < TC / 2; ++i) {
        int r = grp + 2 * i;
        float4 e = *(const float4*)(enc + ((size_t)b * TT + t0 + r) * DD + gl * 4);
        float w0 = wl[0 * TC + r], w1 = wl[1 * TC + r], w2 = wl[2 * TC + r], w3 = wl[3 * TC + r];
        float w4 = wl[4 * TC + r], w5 = wl[5 * TC + r], w6 = wl[6 * TC + r], w7 = wl[7 * TC + r];
        acc[0].x += w0 * e.x; acc[0].y += w0 * e.y; acc[0].z += w0 * e.z; acc[0].w += w0 * e.w;
        acc[1].x += w1 * e.x; acc[1].y += w1 * e.y; acc[1].z += w1 * e.z; acc[1].w += w1 * e.w;
        acc[2].x += w2 * e.x; acc[2].y += w2 * e.y; acc[2].z += w2 * e.z; acc[2].w += w2 * e.w;
        acc[3].x += w3 * e.x; acc[3].y += w3 * e.y; acc[3].z += w3 * e.z; acc[3].w += w3 * e.w;
        acc[4].x += w4 * e.x; acc[4].y += w4 * e.y; acc[4].z += w4 * e.z; acc[4].w += w4 * e.w;
        acc[5].x += w5 * e.x; acc[5].y += w5 * e.y; acc[5].z += w5 * e.z; acc[5].w += w5 * e.w;
        acc[6].x += w6 * e.x; acc[6].y += w6 * e.y; acc[6].z += w6 * e.z; acc[6].w += w6 * e.w;
        acc[7].x += w7 * e.x; acc[7].y += w7 * e.y; acc[7].z += w7 * e.z; acc[7].w += w7 * e.w;
    }
    if (grp == 1) {
#pragma unroll
        for (int h = 0; h < HH; ++h) *(float4*)(mrg + h * DD + gl * 4) = acc[h];
    }
    __syncthreads();
    if (grp == 0) {
        float* pp = partial + (size_t)(b * CHUNKS + c) * HH * DD + gl * 4;
#pragma unroll
        for (int h = 0; h < HH; ++h) {
            float4 m = *(const float4*)(mrg + h * DD + gl * 4);
            float4 r = acc[h];
            r.x += m.x; r.y += m.y; r.z += m.z; r.w += m.w;
            *(float4*)(pp + h * DD) = r;
        }
    }
}

// ---------------- F: ctx[b,h*D+d] = sum_c partial  (coalesced, 128 blocks) ----
__global__ __launch_bounds__(256) void k_pred(const float* __restrict__ partial,
                                              float* __restrict__ ctx) {
    int idx = blockIdx.x * 256 + threadIdx.x;   // over B*H*D/4
    int b = idx >> 10, r4 = (idx & 1023) * 4;
    const float* pp = partial + (size_t)b * CHUNKS * HH * DD + r4;
    float4 acc = make_float4(0.f, 0.f, 0.f, 0.f);
#pragma unroll 8
    for (int c = 0; c < CHUNKS; ++c) {
        float4 v = *(const float4*)(pp + (size_t)c * HH * DD);
        acc.x += v.x; acc.y += v.y; acc.z += v.z; acc.w += v.w;
    }
    *(float4*)(ctx + (size_t)b * HH * DD + r4) = acc;
}

// ---------------- G: ctxv = blockdiag(Wv) ctx ; out0 = Wo ctxv ----------------
__global__ __launch_bounds__(256) void k_vo(const float* __restrict__ ctx,
                                            const float* __restrict__ Wv,
                                            const float* __restrict__ Wo,
                                            float* __restrict__ out0) {
    __shared__ float cx[HH * DD];
    __shared__ float cv[DD];
    int b = blockIdx.x, tid = threadIdx.x;
    for (int i = tid; i < HH * DD; i += 256) cx[i] = ctx[(size_t)b * HH * DD + i];
    __syncthreads();
#pragma unroll
    for (int k = 0; k < 2; ++k) {
        int i = tid + 256 * k;
        int h = i >> 6;
        const float4* wr = (const float4*)(Wv + (size_t)i * DD);
        const float* cc = cx + h * DD;
        float acc = 0.f;
#pragma unroll 4
        for (int d = 0; d < DD / 4; ++d) {
            float4 w = wr[d];
            acc += w.x * cc[4 * d] + w.y * cc[4 * d + 1] + w.z * cc[4 * d + 2] + w.w * cc[4 * d + 3];
        }
        cv[i] = acc;
    }
    __syncthreads();
#pragma unroll
    for (int k = 0; k < 2; ++k) {
        int o = tid + 256 * k;
        const float4* wr = (const float4*)(Wo + (size_t)o * DD);
        float acc = 0.f;
#pragma unroll 4
        for (int d = 0; d < DD / 4; ++d) {
            float4 w = wr[d];
            acc += w.x * cv[4 * d] + w.y * cv[4 * d + 1] + w.z * cv[4 * d + 2] + w.w * cv[4 * d + 3];
        }
        out0[(size_t)b * DD + o] = acc;
    }
}

extern "C" void kernel_launch(void* const* d_in, const int* in_sizes, int n_in,
                              void* d_out, int out_size, void* d_ws, size_t ws_size,
                              hipStream_t stream) {
    const float* enc = (const float*)d_in[0];
    const float* Wq  = (const float*)d_in[1];
    const float* Wk  = (const float*)d_in[2];
    const float* Wv  = (const float*)d_in[3];
    const float* Wo  = (const float*)d_in[4];

    float* ws = (float*)d_ws;
    float* u       = ws;                               // B*H*D     = 131072
    float* scores  = u + (size_t)BB * HH * DD;         // B*H*T     = 1048576
    float* weights = scores + (size_t)BB * TT * HH;    // B*H*T     = 1048576
    float* partial = weights + (size_t)BB * TT * HH;   // B*32*H*D  = 4194304
    float* ctx     = partial + (size_t)BB * CHUNKS * HH * DD; // B*H*D = 131072
    // total ~6.6M floats (~26 MB)

    float* out0 = (float*)d_out;          // [B, D]
    float* out1 = out0 + BB * DD;         // [B, T]

    hipLaunchKernelGGL(k_qu,      dim3(BB * HH),      dim3(256), 0, stream, enc, Wq, Wk, u);
    hipLaunchKernelGGL(k_scores,  dim3(BB * 64),      dim3(256), 0, stream, enc, u, scores);
    hipLaunchKernelGGL(k_softmax, dim3(BB * HH),      dim3(256), 0, stream, scores, weights);
    hipLaunchKernelGGL(k_wsum,    dim3(BB * CHUNKS),  dim3(256), 0, stream, enc, weights, partial, out1);
    hipLaunchKernelGGL(k_pred,    dim3(BB * HH * DD / 1024), dim3(256), 0, stream, partial, ctx);
    hipLaunchKernelGGL(k_vo,      dim3(BB),           dim3(256), 0, stream, ctx, Wv, Wo, out0);
}